// Round 1
// baseline (5788.680 us; speedup 1.0000x reference)
//
#include <hip/hip_runtime.h>
#include <math.h>

#define B_   8
#define C_   256
#define N_   4096
#define CQK_ 64
#define JSPLIT 8

// ---------------------------------------------------------------- add: xs = x + xyz
__global__ __launch_bounds__(256) void add_kernel(const float4* __restrict__ a,
                                                  const float4* __restrict__ b,
                                                  float4* __restrict__ o) {
    size_t i = (size_t)blockIdx.x * 256 + threadIdx.x;
    float4 av = a[i], bv = b[i];
    o[i] = make_float4(av.x + bv.x, av.y + bv.y, av.z + bv.z, av.w + bv.w);
}

// ------------------------------------------------- conv1x1: Y[b,o,n] = sum_c W[o,c]X[b,c,n]+bias
// block: 256 threads -> (o-tile 64) x (n-tile 256). W staged transposed in LDS, X in regs.
__global__ __launch_bounds__(256) void conv1x1_kernel(const float* __restrict__ X,
                                                      const float* __restrict__ W,
                                                      const float* __restrict__ bias,
                                                      float* __restrict__ Y, int Cout) {
    __shared__ __align__(16) float sw[64][68];   // [cc][o], pad 68 keeps float4 rows 16B-aligned
    const int tid = threadIdx.x;
    const int n0 = blockIdx.x * 256;
    const int o0 = blockIdx.y * 64;
    const int b  = blockIdx.z;
    const float* Xb = X + (size_t)b * C_ * N_;
    float acc[64];
#pragma unroll
    for (int o = 0; o < 64; ++o) acc[o] = 0.f;

    for (int c0 = 0; c0 < C_; c0 += 64) {
        float xreg[64];
#pragma unroll
        for (int cc = 0; cc < 64; ++cc)
            xreg[cc] = Xb[(size_t)(c0 + cc) * N_ + n0 + tid];
        __syncthreads();   // previous chunk's compute done before overwriting sw
        for (int r = 0; r < 16; ++r) {
            int idx = r * 256 + tid;
            int o = idx >> 6, cc = idx & 63;
            sw[cc][o] = W[(size_t)(o0 + o) * C_ + c0 + cc];
        }
        __syncthreads();
#pragma unroll
        for (int cc = 0; cc < 64; ++cc) {
            float xv = xreg[cc];
            const float4* wr = (const float4*)&sw[cc][0];
#pragma unroll
            for (int o4 = 0; o4 < 16; ++o4) {
                float4 w4 = wr[o4];
                acc[o4 * 4 + 0] += w4.x * xv;
                acc[o4 * 4 + 1] += w4.y * xv;
                acc[o4 * 4 + 2] += w4.z * xv;
                acc[o4 * 4 + 3] += w4.w * xv;
            }
        }
    }
#pragma unroll
    for (int o = 0; o < 64; ++o)
        Y[((size_t)b * Cout + o0 + o) * N_ + n0 + tid] = acc[o] + bias[o0 + o];
}

// ------------------------------------------- pass A: per-row online softmax stats of e = Q^T Q
__global__ __launch_bounds__(256) void rowstats_kernel(const float* __restrict__ Q,
                                                       float* __restrict__ pmax,
                                                       float* __restrict__ psum) {
    __shared__ __align__(16) float sqT[64][68];  // [j][c]
    const int tid = threadIdx.x;
    const int b = blockIdx.y, js = blockIdx.z;
    const int i = blockIdx.x * 256 + tid;        // this thread's row
    const float* Qb = Q + (size_t)b * CQK_ * N_;
    float qreg[64];
#pragma unroll
    for (int c = 0; c < 64; ++c) qreg[c] = Qb[(size_t)c * N_ + i];

    float m = -1e30f, s = 0.f;
    const int jbeg = js * (N_ / JSPLIT);
    for (int j0 = jbeg; j0 < jbeg + N_ / JSPLIT; j0 += 64) {
        __syncthreads();
        for (int r = 0; r < 16; ++r) {
            int idx = r * 256 + tid;
            int c = idx >> 6, j = idx & 63;
            sqT[j][c] = Qb[(size_t)c * N_ + j0 + j];   // coalesced global read
        }
        __syncthreads();
        for (int jj = 0; jj < 64; ++jj) {
            const float4* qj = (const float4*)&sqT[jj][0];
            float e[4] = {0.f, 0.f, 0.f, 0.f};
#pragma unroll
            for (int c4 = 0; c4 < 16; ++c4) {
                float4 q4 = qj[c4];
                e[c4 & 3] += q4.x * qreg[c4 * 4 + 0] + q4.y * qreg[c4 * 4 + 1]
                           + q4.z * qreg[c4 * 4 + 2] + q4.w * qreg[c4 * 4 + 3];
            }
            float ee = (e[0] + e[1]) + (e[2] + e[3]);
            float mn = fmaxf(m, ee);
            s = s * __expf(m - mn) + __expf(ee - mn);
            m = mn;
        }
    }
    size_t o = ((size_t)js * B_ + b) * N_ + i;
    pmax[o] = m;
    psum[o] = s;
}

__global__ __launch_bounds__(256) void rowmerge_kernel(const float* __restrict__ pmax,
                                                       const float* __restrict__ psum,
                                                       float* __restrict__ rm,
                                                       float* __restrict__ rsinv) {
    size_t i = (size_t)blockIdx.x * 256 + threadIdx.x;   // over B_*N_
    float m = -1e30f;
#pragma unroll
    for (int js = 0; js < JSPLIT; ++js) m = fmaxf(m, pmax[(size_t)js * B_ * N_ + i]);
    float s = 0.f;
#pragma unroll
    for (int js = 0; js < JSPLIT; ++js)
        s += psum[(size_t)js * B_ * N_ + i] * __expf(pmax[(size_t)js * B_ * N_ + i] - m);
    rm[i] = m;
    rsinv[i] = 1.f / s;
}

// ------------------- pass B: recompute energy tiles, attn = exp(e-rm)*rsinv,
//                     accumulate colsum[m] and xrU[c,m] = sum_n v[c,n]*attn[n,m]
__global__ __launch_bounds__(256) void pv_kernel(const float* __restrict__ Q,
                                                 const float* __restrict__ V,
                                                 const float* __restrict__ rm,
                                                 const float* __restrict__ rsinv,
                                                 float* __restrict__ xrU,
                                                 float* __restrict__ colsum) {
    __shared__ __align__(16) float sqnT[64][68];  // [n][c]
    __shared__ __align__(16) float sa[64][64];    // [n][m]
    __shared__ float sv[256][65];                 // [c][n], pad 65: conflict-free row reads
    __shared__ float srm[64], srsi[64];
    const int tid = threadIdx.x;
    const int m0 = blockIdx.x * 64;
    const int b  = blockIdx.y;
    const float* Qb = Q + (size_t)b * CQK_ * N_;
    const float* Vb = V + (size_t)b * C_ * N_;
    const int mm  = tid & 63;   // energy phase: this thread's m column
    const int nnb = tid >> 6;   // energy phase: wave id -> n sub-row
    const int cg  = tid >> 2;   // PV phase: c-group (4 channels)
    const int mq  = tid & 3;    // PV phase: m-quarter (16 columns)

    float qmreg[64];
#pragma unroll
    for (int c = 0; c < 64; ++c) qmreg[c] = Qb[(size_t)c * N_ + m0 + mm];

    float acc[64];   // [u 0..3][w 0..15] -> c = cg*4+u, m = m0 + mq*16 + w
#pragma unroll
    for (int k = 0; k < 64; ++k) acc[k] = 0.f;
    float creg = 0.f;

    for (int n0 = 0; n0 < N_; n0 += 64) {
        __syncthreads();   // previous tile fully consumed
        for (int r = 0; r < 16; ++r) {
            int idx = r * 256 + tid;
            int c = idx >> 6, nn = idx & 63;
            sqnT[nn][c] = Qb[(size_t)c * N_ + n0 + nn];
        }
        for (int r = 0; r < 64; ++r) {
            int idx = r * 256 + tid;
            int c = idx >> 6, nn = idx & 63;
            sv[c][nn] = Vb[(size_t)c * N_ + n0 + nn];
        }
        if (tid < 64) {
            srm[tid]  = rm[(size_t)b * N_ + n0 + tid];
            srsi[tid] = rsinv[(size_t)b * N_ + n0 + tid];
        }
        __syncthreads();

        // energy + attn tile: each thread computes 16 (nn, mm) entries
#pragma unroll
        for (int r = 0; r < 16; ++r) {
            int nn = r * 4 + nnb;
            const float4* qn = (const float4*)&sqnT[nn][0];
            float e[4] = {0.f, 0.f, 0.f, 0.f};
#pragma unroll
            for (int c4 = 0; c4 < 16; ++c4) {
                float4 q4 = qn[c4];
                e[c4 & 3] += q4.x * qmreg[c4 * 4 + 0] + q4.y * qmreg[c4 * 4 + 1]
                           + q4.z * qmreg[c4 * 4 + 2] + q4.w * qmreg[c4 * 4 + 3];
            }
            float ee = (e[0] + e[1]) + (e[2] + e[3]);
            sa[nn][mm] = __expf(ee - srm[nn]) * srsi[nn];
        }
        __syncthreads();

        // PV accumulate: thread owns 4 channels x 16 columns
        for (int nn = 0; nn < 64; ++nn) {
            float v0 = sv[cg * 4 + 0][nn];
            float v1 = sv[cg * 4 + 1][nn];
            float v2 = sv[cg * 4 + 2][nn];
            float v3 = sv[cg * 4 + 3][nn];
            const float4* ar = (const float4*)&sa[nn][mq * 16];
#pragma unroll
            for (int w = 0; w < 4; ++w) {
                float4 a4 = ar[w];
                acc[0 * 16 + w * 4 + 0] += v0 * a4.x;
                acc[0 * 16 + w * 4 + 1] += v0 * a4.y;
                acc[0 * 16 + w * 4 + 2] += v0 * a4.z;
                acc[0 * 16 + w * 4 + 3] += v0 * a4.w;
                acc[1 * 16 + w * 4 + 0] += v1 * a4.x;
                acc[1 * 16 + w * 4 + 1] += v1 * a4.y;
                acc[1 * 16 + w * 4 + 2] += v1 * a4.z;
                acc[1 * 16 + w * 4 + 3] += v1 * a4.w;
                acc[2 * 16 + w * 4 + 0] += v2 * a4.x;
                acc[2 * 16 + w * 4 + 1] += v2 * a4.y;
                acc[2 * 16 + w * 4 + 2] += v2 * a4.z;
                acc[2 * 16 + w * 4 + 3] += v2 * a4.w;
                acc[3 * 16 + w * 4 + 0] += v3 * a4.x;
                acc[3 * 16 + w * 4 + 1] += v3 * a4.y;
                acc[3 * 16 + w * 4 + 2] += v3 * a4.z;
                acc[3 * 16 + w * 4 + 3] += v3 * a4.w;
            }
        }
        if (tid < 64) {   // column sums of this attn tile
            float cs = 0.f;
            for (int nn = 0; nn < 64; ++nn) cs += sa[nn][tid];
            creg += cs;
        }
    }

    if (tid < 64) colsum[(size_t)b * N_ + m0 + tid] = creg;
#pragma unroll
    for (int u = 0; u < 4; ++u)
#pragma unroll
        for (int w = 0; w < 4; ++w) {
            float4 o4 = make_float4(acc[u * 16 + w * 4 + 0], acc[u * 16 + w * 4 + 1],
                                    acc[u * 16 + w * 4 + 2], acc[u * 16 + w * 4 + 3]);
            *(float4*)&xrU[((size_t)b * C_ + cg * 4 + u) * N_ + m0 + mq * 16 + w * 4] = o4;
        }
}

// ---------------------------------- d = xs - xrU / (1e-9 + colsum[m])   (in place into xrU)
__global__ __launch_bounds__(256) void diff_kernel(const float* __restrict__ xs,
                                                   float* __restrict__ xr,
                                                   const float* __restrict__ colsum) {
    size_t i4 = (size_t)blockIdx.x * 256 + threadIdx.x;
    size_t i = i4 * 4;
    int m = (int)(i % N_);
    int b = (int)(i / ((size_t)C_ * N_));
    float4 cs = *(const float4*)&colsum[(size_t)b * N_ + m];
    float4 xv = ((const float4*)xs)[i4];
    float4 rv = ((float4*)xr)[i4];
    float4 d;
    d.x = xv.x - rv.x / (1e-9f + cs.x);
    d.y = xv.y - rv.y / (1e-9f + cs.y);
    d.z = xv.z - rv.z / (1e-9f + cs.z);
    d.w = xv.w - rv.w / (1e-9f + cs.w);
    ((float4*)xr)[i4] = d;
}

// ------------------------------------- out = xs + leakyrelu(bn(t))  (BN eval, running stats)
__global__ __launch_bounds__(256) void finalize_kernel(const float* __restrict__ xs,
                                                       const float* __restrict__ t,
                                                       float* __restrict__ out,
                                                       const float* __restrict__ gamma,
                                                       const float* __restrict__ beta,
                                                       const float* __restrict__ mean,
                                                       const float* __restrict__ var) {
    size_t i4 = (size_t)blockIdx.x * 256 + threadIdx.x;
    size_t i = i4 * 4;
    int c = (int)((i / N_) % C_);
    float sc = rsqrtf(var[c] + 1e-5f) * gamma[c];
    float sh = beta[c] - mean[c] * sc;
    float4 tv = ((const float4*)t)[i4];
    float4 xv = ((const float4*)xs)[i4];
    float4 o;
    float tn;
    tn = tv.x * sc + sh; o.x = xv.x + (tn >= 0.f ? tn : 0.2f * tn);
    tn = tv.y * sc + sh; o.y = xv.y + (tn >= 0.f ? tn : 0.2f * tn);
    tn = tv.z * sc + sh; o.z = xv.z + (tn >= 0.f ? tn : 0.2f * tn);
    tn = tv.w * sc + sh; o.w = xv.w + (tn >= 0.f ? tn : 0.2f * tn);
    ((float4*)out)[i4] = o;
}

// ----------------------------------------------------------------------------------------
extern "C" void kernel_launch(void* const* d_in, const int* in_sizes, int n_in,
                              void* d_out, int out_size, void* d_ws, size_t ws_size,
                              hipStream_t stream) {
    (void)in_sizes; (void)n_in; (void)out_size; (void)ws_size;
    const float* x   = (const float*)d_in[0];
    const float* xyz = (const float*)d_in[1];
    const float* wqk = (const float*)d_in[2];
    const float* bqk = (const float*)d_in[3];
    const float* wv  = (const float*)d_in[4];
    const float* bv  = (const float*)d_in[5];
    const float* wt  = (const float*)d_in[6];
    const float* bt  = (const float*)d_in[7];
    const float* gam = (const float*)d_in[8];
    const float* bet = (const float*)d_in[9];
    const float* mu  = (const float*)d_in[10];
    const float* var = (const float*)d_in[11];
    float* out = (float*)d_out;

    // workspace layout (floats): xs | Q | V(->t) | pmax | psum | rm | rsinv | colsum  (~78 MB)
    float* ws   = (float*)d_ws;
    float* xs   = ws;
    float* Qb   = xs + (size_t)B_ * C_ * N_;
    float* Vb   = Qb + (size_t)B_ * CQK_ * N_;
    float* tbuf = Vb;   // V buffer reused for t after pv
    float* pmax = Vb + (size_t)B_ * C_ * N_;
    float* psum = pmax + (size_t)JSPLIT * B_ * N_;
    float* rmb  = psum + (size_t)JSPLIT * B_ * N_;
    float* rsb  = rmb + (size_t)B_ * N_;
    float* csb  = rsb + (size_t)B_ * N_;
    float* xr   = out;  // xrU lives in d_out until diff/conv consume it

    const int ELT4_BLOCKS = (B_ * C_ * N_) / 4 / 256;   // 8192

    add_kernel<<<dim3(ELT4_BLOCKS), dim3(256), 0, stream>>>(
        (const float4*)x, (const float4*)xyz, (float4*)xs);
    conv1x1_kernel<<<dim3(N_ / 256, CQK_ / 64, B_), dim3(256), 0, stream>>>(
        xs, wqk, bqk, Qb, CQK_);
    conv1x1_kernel<<<dim3(N_ / 256, C_ / 64, B_), dim3(256), 0, stream>>>(
        xs, wv, bv, Vb, C_);
    rowstats_kernel<<<dim3(N_ / 256, B_, JSPLIT), dim3(256), 0, stream>>>(Qb, pmax, psum);
    rowmerge_kernel<<<dim3(B_ * N_ / 256), dim3(256), 0, stream>>>(pmax, psum, rmb, rsb);
    pv_kernel<<<dim3(N_ / 64, B_), dim3(256), 0, stream>>>(Qb, Vb, rmb, rsb, xr, csb);
    diff_kernel<<<dim3(ELT4_BLOCKS), dim3(256), 0, stream>>>(xs, xr, csb);
    conv1x1_kernel<<<dim3(N_ / 256, C_ / 64, B_), dim3(256), 0, stream>>>(
        xr, wt, bt, tbuf, C_);
    finalize_kernel<<<dim3(ELT4_BLOCKS), dim3(256), 0, stream>>>(
        xs, tbuf, out, gam, bet, mu, var);
}

// Round 2
// 621.554 us; speedup vs baseline: 9.3132x; 9.3132x over previous
//
#include <hip/hip_runtime.h>
#include <math.h>

#define B_   8
#define C_   256
#define N_   4096
#define CQK_ 64
#define JS_  4

typedef __attribute__((ext_vector_type(8))) short short8v;   // 8 x bf16 (4 VGPRs)
typedef __attribute__((ext_vector_type(4))) float f32x4;

__device__ __forceinline__ unsigned short f2bf(float f) {
    unsigned u = __float_as_uint(f);
    u += 0x7fffu + ((u >> 16) & 1u);
    return (unsigned short)(u >> 16);
}

// ---------------------------------------------------------------- add: xs = x + xyz
__global__ __launch_bounds__(256) void add_kernel(const float4* __restrict__ a,
                                                  const float4* __restrict__ b,
                                                  float4* __restrict__ o) {
    size_t i = (size_t)blockIdx.x * 256 + threadIdx.x;
    float4 av = a[i], bv = b[i];
    o[i] = make_float4(av.x + bv.x, av.y + bv.y, av.z + bv.z, av.w + bv.w);
}

// ------------------------------------------------- conv1x1: Y[b,o,n] = sum_c W[o,c]X[b,c,n]+bias
// MODE 0: fp32 out [b][o][n]; MODE 1: bf16 out [b][o][n]; MODE 2: bf16 transposed [b][n][o] (Cout=64)
template<int MODE>
__global__ __launch_bounds__(256) void conv1x1_kernel(const float* __restrict__ X,
                                                      const float* __restrict__ W,
                                                      const float* __restrict__ bias,
                                                      float* __restrict__ Yf,
                                                      unsigned short* __restrict__ Yh,
                                                      int Cout) {
    __shared__ __align__(16) float sw[64][68];
    const int tid = threadIdx.x;
    const int n0 = blockIdx.x * 256;
    const int o0 = blockIdx.y * 64;
    const int b  = blockIdx.z;
    const float* Xb = X + (size_t)b * C_ * N_;
    float acc[64];
#pragma unroll
    for (int o = 0; o < 64; ++o) acc[o] = 0.f;

    for (int c0 = 0; c0 < C_; c0 += 64) {
        float xreg[64];
#pragma unroll
        for (int cc = 0; cc < 64; ++cc)
            xreg[cc] = Xb[(size_t)(c0 + cc) * N_ + n0 + tid];
        __syncthreads();
        for (int r = 0; r < 16; ++r) {
            int idx = r * 256 + tid;
            int o = idx >> 6, cc = idx & 63;
            sw[cc][o] = W[(size_t)(o0 + o) * C_ + c0 + cc];
        }
        __syncthreads();
#pragma unroll
        for (int cc = 0; cc < 64; ++cc) {
            float xv = xreg[cc];
            const float4* wr = (const float4*)&sw[cc][0];
#pragma unroll
            for (int o4 = 0; o4 < 16; ++o4) {
                float4 w4 = wr[o4];
                acc[o4 * 4 + 0] += w4.x * xv;
                acc[o4 * 4 + 1] += w4.y * xv;
                acc[o4 * 4 + 2] += w4.z * xv;
                acc[o4 * 4 + 3] += w4.w * xv;
            }
        }
    }
    if (MODE == 0) {
#pragma unroll
        for (int o = 0; o < 64; ++o)
            Yf[((size_t)b * Cout + o0 + o) * N_ + n0 + tid] = acc[o] + bias[o0 + o];
    } else if (MODE == 1) {
#pragma unroll
        for (int o = 0; o < 64; ++o)
            Yh[((size_t)b * Cout + o0 + o) * N_ + n0 + tid] = f2bf(acc[o] + bias[o0 + o]);
    } else {  // transposed bf16: Qt[b][n][o], Cout == 64, o0 == 0
#pragma unroll
        for (int o8 = 0; o8 < 8; ++o8) {
            short8v v;
#pragma unroll
            for (int j = 0; j < 8; ++j) v[j] = (short)f2bf(acc[o8 * 8 + j] + bias[o8 * 8 + j]);
            *(short8v*)(Yh + ((size_t)b * N_ + n0 + tid) * 64 + o8 * 8) = v;
        }
    }
}

// ------------------------------------------- pass A: per-row online softmax stats via MFMA
// E^T[j][i] = sum_c Q[c][j] Q[c][i]; each wave owns 16 rows i, loops j.
__global__ __launch_bounds__(256) void rowstats_mfma(const unsigned short* __restrict__ Qt,
                                                     float* __restrict__ pmax,
                                                     float* __restrict__ psum) {
    const int tid = threadIdx.x;
    const int wave = tid >> 6, lane = tid & 63, q = lane & 15, g = lane >> 4;
    const int bid = blockIdx.x;
    const int b  = bid & 7;
    const int it = (bid >> 3) & 63;
    const int js = bid >> 9;
    const int i0 = it * 64 + wave * 16;
    const unsigned short* Qb = Qt + (size_t)b * N_ * CQK_;

    const unsigned short* bp = Qb + (size_t)(i0 + q) * CQK_ + 8 * g;
    short8v bq0 = *(const short8v*)bp;
    short8v bq1 = *(const short8v*)(bp + 32);

    float m = -1e30f, s = 0.f;
    const int jbeg = js * (N_ / JS_);
    for (int j0 = jbeg; j0 < jbeg + N_ / JS_; j0 += 16) {
        const unsigned short* ap = Qb + (size_t)(j0 + q) * CQK_ + 8 * g;
        short8v a0 = *(const short8v*)ap;
        short8v a1 = *(const short8v*)(ap + 32);
        f32x4 e = {0.f, 0.f, 0.f, 0.f};
        e = __builtin_amdgcn_mfma_f32_16x16x32_bf16(a0, bq0, e, 0, 0, 0);
        e = __builtin_amdgcn_mfma_f32_16x16x32_bf16(a1, bq1, e, 0, 0, 0);
#pragma unroll
        for (int r = 0; r < 4; ++r) {
            float ee = e[r];
            float mn = fmaxf(m, ee);
            s = s * __expf(m - mn) + __expf(ee - mn);
            m = mn;
        }
    }
#pragma unroll
    for (int off = 16; off <= 32; off <<= 1) {
        float mo = __shfl_xor(m, off);
        float so = __shfl_xor(s, off);
        float mn = fmaxf(m, mo);
        s = s * __expf(m - mn) + so * __expf(mo - mn);
        m = mn;
    }
    if (lane < 16) {
        size_t o = ((size_t)js * B_ + b) * N_ + i0 + q;
        pmax[o] = m;
        psum[o] = s;
    }
}

__global__ __launch_bounds__(256) void rowmerge_kernel(const float* __restrict__ pmax,
                                                       const float* __restrict__ psum,
                                                       float* __restrict__ rm,
                                                       float* __restrict__ rsinv) {
    size_t i = (size_t)blockIdx.x * 256 + threadIdx.x;
    float m = -1e30f;
#pragma unroll
    for (int js = 0; js < JS_; ++js) m = fmaxf(m, pmax[(size_t)js * B_ * N_ + i]);
    float s = 0.f;
#pragma unroll
    for (int js = 0; js < JS_; ++js)
        s += psum[(size_t)js * B_ * N_ + i] * __expf(pmax[(size_t)js * B_ * N_ + i] - m);
    rm[i] = m;
    rsinv[i] = 1.f / s;
}

// ------------------- pass B (MFMA): energy tile -> attn (LDS, swizzled) -> PV accumulate
__global__ __launch_bounds__(512, 4) void pv_mfma(const unsigned short* __restrict__ Qt,
                                                  const unsigned short* __restrict__ Vh,
                                                  const float* __restrict__ rm,
                                                  const float* __restrict__ rsinv,
                                                  float* __restrict__ xr,
                                                  float* __restrict__ colsum) {
    __shared__ unsigned short saT[64 * 64];   // [m][n] bf16, 128B pitch, XOR-swizzled
    __shared__ float scs[8][2][16];
    const int tid = threadIdx.x;
    const int wave = tid >> 6, lane = tid & 63, q = lane & 15, g = lane >> 4;
    const int bid = blockIdx.x;
    const int b  = bid & 7;                // XCD-pinned: one batch per XCD
    const int m0 = (bid >> 3) << 6;
    const int nb = wave & 3, mp = wave >> 2;
    const unsigned short* Qb = Qt + (size_t)b * N_ * CQK_;
    const unsigned short* Vb = Vh + (size_t)b * C_ * N_;
    const float* rmb = rm + (size_t)b * N_;
    const float* rsb = rsinv + (size_t)b * N_;

    short8v bqm[2][2];   // energy B-frags: Q columns m (2 m-blocks x 2 k-chunks)
#pragma unroll
    for (int mi = 0; mi < 2; ++mi) {
        const unsigned short* p = Qb + (size_t)(m0 + (mp * 2 + mi) * 16 + q) * CQK_ + 8 * g;
        bqm[mi][0] = *(const short8v*)p;
        bqm[mi][1] = *(const short8v*)(p + 32);
    }

    f32x4 acc[2][4];
#pragma unroll
    for (int ci = 0; ci < 2; ++ci)
#pragma unroll
        for (int mb = 0; mb < 4; ++mb) acc[ci][mb] = (f32x4){0.f, 0.f, 0.f, 0.f};
    float csum0 = 0.f, csum1 = 0.f;

    for (int n0 = 0; n0 < N_; n0 += 64) {
        __syncthreads();   // previous tile's saT reads complete
        {   // ---- energy: E rows nb*16..+16, cols mp*32..+32
            const unsigned short* p = Qb + (size_t)(n0 + nb * 16 + q) * CQK_ + 8 * g;
            short8v an0 = *(const short8v*)p;
            short8v an1 = *(const short8v*)(p + 32);
            f32x4 rm4 = *(const f32x4*)(rmb + n0 + nb * 16 + 4 * g);
            f32x4 rs4 = *(const f32x4*)(rsb + n0 + nb * 16 + 4 * g);
#pragma unroll
            for (int mi = 0; mi < 2; ++mi) {
                f32x4 e = {0.f, 0.f, 0.f, 0.f};
                e = __builtin_amdgcn_mfma_f32_16x16x32_bf16(an0, bqm[mi][0], e, 0, 0, 0);
                e = __builtin_amdgcn_mfma_f32_16x16x32_bf16(an1, bqm[mi][1], e, 0, 0, 0);
                const int mcol = (mp * 2 + mi) * 16 + q;
                const int rowbase = mcol * 128;
                const int sw = (mcol & 7) << 4;
#pragma unroll
                for (int r = 0; r < 4; ++r) {
                    float a = __expf(e[r] - rm4[r]) * rs4[r];
                    if (mi == 0) csum0 += a; else csum1 += a;
                    int nl = nb * 16 + 4 * g + r;
                    *(unsigned short*)((char*)saT + rowbase + ((2 * nl) ^ sw)) = f2bf(a);
                }
            }
        }
        __syncthreads();   // saT fully written
        // ---- PV: XR[c][m] += V[c][n] * a[n][m]
#pragma unroll
        for (int ch = 0; ch < 2; ++ch) {
            short8v bfrag[4];
#pragma unroll
            for (int mb = 0; mb < 4; ++mb) {
                int row = mb * 16 + q;
                int byte = row * 128 + (((g + 4 * ch) * 16) ^ ((row & 7) << 4));
                bfrag[mb] = *(const short8v*)((char*)saT + byte);
            }
#pragma unroll
            for (int ci = 0; ci < 2; ++ci) {
                const unsigned short* vp =
                    Vb + (size_t)(wave * 32 + ci * 16 + q) * N_ + n0 + ch * 32 + 8 * g;
                short8v vf = *(const short8v*)vp;
#pragma unroll
                for (int mb = 0; mb < 4; ++mb)
                    acc[ci][mb] = __builtin_amdgcn_mfma_f32_16x16x32_bf16(vf, bfrag[mb],
                                                                          acc[ci][mb], 0, 0, 0);
            }
        }
    }

    csum0 += __shfl_xor(csum0, 16); csum0 += __shfl_xor(csum0, 32);
    csum1 += __shfl_xor(csum1, 16); csum1 += __shfl_xor(csum1, 32);
    if (lane < 16) { scs[wave][0][q] = csum0; scs[wave][1][q] = csum1; }
    __syncthreads();
    if (tid < 64) {
        int mb = tid >> 4, qq = tid & 15;
        int base = (mb >> 1) * 4;
        float cs = 0.f;
#pragma unroll
        for (int w = 0; w < 4; ++w) cs += scs[base + w][mb & 1][qq];
        colsum[(size_t)b * N_ + m0 + tid] = cs;
    }
#pragma unroll
    for (int ci = 0; ci < 2; ++ci) {
        int c = wave * 32 + ci * 16 + 4 * g;
#pragma unroll
        for (int mb = 0; mb < 4; ++mb)
#pragma unroll
            for (int r = 0; r < 4; ++r)
                xr[((size_t)b * C_ + c + r) * N_ + m0 + mb * 16 + q] = acc[ci][mb][r];
    }
}

// ---------------------------------- d = xs - xr / (1e-9 + colsum[m])   (in place into xr)
__global__ __launch_bounds__(256) void diff_kernel(const float* __restrict__ xs,
                                                   float* __restrict__ xr,
                                                   const float* __restrict__ colsum) {
    size_t i4 = (size_t)blockIdx.x * 256 + threadIdx.x;
    size_t i = i4 * 4;
    int m = (int)(i % N_);
    int b = (int)(i / ((size_t)C_ * N_));
    float4 cs = *(const float4*)&colsum[(size_t)b * N_ + m];
    float4 xv = ((const float4*)xs)[i4];
    float4 rv = ((float4*)xr)[i4];
    float4 d;
    d.x = xv.x - rv.x / (1e-9f + cs.x);
    d.y = xv.y - rv.y / (1e-9f + cs.y);
    d.z = xv.z - rv.z / (1e-9f + cs.z);
    d.w = xv.w - rv.w / (1e-9f + cs.w);
    ((float4*)xr)[i4] = d;
}

// ------------------------------------- out = xs + leakyrelu(bn(t))
__global__ __launch_bounds__(256) void finalize_kernel(const float* __restrict__ xs,
                                                       const float* __restrict__ t,
                                                       float* __restrict__ out,
                                                       const float* __restrict__ gamma,
                                                       const float* __restrict__ beta,
                                                       const float* __restrict__ mean,
                                                       const float* __restrict__ var) {
    size_t i4 = (size_t)blockIdx.x * 256 + threadIdx.x;
    size_t i = i4 * 4;
    int c = (int)((i / N_) % C_);
    float sc = rsqrtf(var[c] + 1e-5f) * gamma[c];
    float sh = beta[c] - mean[c] * sc;
    float4 tv = ((const float4*)t)[i4];
    float4 xv = ((const float4*)xs)[i4];
    float4 o;
    float tn;
    tn = tv.x * sc + sh; o.x = xv.x + (tn >= 0.f ? tn : 0.2f * tn);
    tn = tv.y * sc + sh; o.y = xv.y + (tn >= 0.f ? tn : 0.2f * tn);
    tn = tv.z * sc + sh; o.z = xv.z + (tn >= 0.f ? tn : 0.2f * tn);
    tn = tv.w * sc + sh; o.w = xv.w + (tn >= 0.f ? tn : 0.2f * tn);
    ((float4*)out)[i4] = o;
}

// ----------------------------------------------------------------------------------------
extern "C" void kernel_launch(void* const* d_in, const int* in_sizes, int n_in,
                              void* d_out, int out_size, void* d_ws, size_t ws_size,
                              hipStream_t stream) {
    (void)in_sizes; (void)n_in; (void)out_size; (void)ws_size;
    const float* x   = (const float*)d_in[0];
    const float* xyz = (const float*)d_in[1];
    const float* wqk = (const float*)d_in[2];
    const float* bqk = (const float*)d_in[3];
    const float* wv  = (const float*)d_in[4];
    const float* bv  = (const float*)d_in[5];
    const float* wt  = (const float*)d_in[6];
    const float* bt  = (const float*)d_in[7];
    const float* gam = (const float*)d_in[8];
    const float* bet = (const float*)d_in[9];
    const float* mu  = (const float*)d_in[10];
    const float* var = (const float*)d_in[11];
    float* out = (float*)d_out;

    const size_t M8 = (size_t)B_ * C_ * N_;        // 8M floats
    float* ws   = (float*)d_ws;
    float* xs   = ws;                               // 8M f32
    unsigned short* Qt = (unsigned short*)(xs + M8);        // B*N*64 bf16 = 1M floats
    float* vtr  = xs + M8 + M8 / 8;                 // 8M f32 region: Vh (bf16) then tbuf (f32)
    unsigned short* Vh = (unsigned short*)vtr;
    float* tbuf = vtr;
    float* pmax = vtr + M8;                         // JS_*B*N
    float* psum = pmax + (size_t)JS_ * B_ * N_;
    float* rmb  = psum + (size_t)JS_ * B_ * N_;
    float* rsb  = rmb + (size_t)B_ * N_;
    float* csb  = rsb + (size_t)B_ * N_;
    float* xr   = out;

    const int ELT4_BLOCKS = (B_ * C_ * N_) / 4 / 256;

    add_kernel<<<dim3(ELT4_BLOCKS), dim3(256), 0, stream>>>(
        (const float4*)x, (const float4*)xyz, (float4*)xs);
    conv1x1_kernel<2><<<dim3(N_ / 256, 1, B_), dim3(256), 0, stream>>>(
        xs, wqk, bqk, nullptr, Qt, CQK_);
    conv1x1_kernel<1><<<dim3(N_ / 256, C_ / 64, B_), dim3(256), 0, stream>>>(
        xs, wv, bv, nullptr, Vh, C_);
    rowstats_mfma<<<dim3(B_ * (N_ / 64) * JS_), dim3(256), 0, stream>>>(Qt, pmax, psum);
    rowmerge_kernel<<<dim3(B_ * N_ / 256), dim3(256), 0, stream>>>(pmax, psum, rmb, rsb);
    pv_mfma<<<dim3(B_ * N_ / 64), dim3(512), 0, stream>>>(Qt, Vh, rmb, rsb, xr, csb);
    diff_kernel<<<dim3(ELT4_BLOCKS), dim3(256), 0, stream>>>(xs, xr, csb);
    conv1x1_kernel<0><<<dim3(N_ / 256, C_ / 64, B_), dim3(256), 0, stream>>>(
        xr, wt, bt, tbuf, nullptr, C_);
    finalize_kernel<<<dim3(ELT4_BLOCKS), dim3(256), 0, stream>>>(
        xs, tbuf, out, gam, bet, mu, var);
}

// Round 3
// 433.141 us; speedup vs baseline: 13.3644x; 1.4350x over previous
//
#include <hip/hip_runtime.h>
#include <math.h>

#define B_   8
#define C_   256
#define N_   4096
#define CQK_ 64
#define JS_  4

typedef __attribute__((ext_vector_type(8))) short short8v;   // 8 x bf16 (4 VGPRs)
typedef __attribute__((ext_vector_type(4))) short short4v;   // 4 x bf16 (8B)
typedef __attribute__((ext_vector_type(4))) float f32x4;

__device__ __forceinline__ unsigned short f2bf(float f) {
    unsigned u = __float_as_uint(f);
    u += 0x7fffu + ((u >> 16) & 1u);
    return (unsigned short)(u >> 16);
}

// ------------------------------------------------ weights fp32 -> bf16 (row-major, packed)
__global__ __launch_bounds__(256) void wcvt_kernel(const float* __restrict__ wqk,
                                                   const float* __restrict__ wv,
                                                   const float* __restrict__ wt,
                                                   unsigned short* __restrict__ wh) {
    int i = (blockIdx.x * 256 + threadIdx.x) * 4;   // 144*256*4 = 147456 total
    const float* src; int off;
    if (i < 16384)      { src = wqk; off = i; }
    else if (i < 81920) { src = wv;  off = i - 16384; }
    else                { src = wt;  off = i - 81920; }
    float4 v = *(const float4*)(src + off);
    short4v o;
    o[0] = (short)f2bf(v.x); o[1] = (short)f2bf(v.y);
    o[2] = (short)f2bf(v.z); o[3] = (short)f2bf(v.w);
    *(short4v*)(wh + i) = o;
}

// --------------------------- xs = x + xyz (fp32 [b][c][n]) AND xst bf16 transposed [b][n][c]
__global__ __launch_bounds__(256) void addt_kernel(const float* __restrict__ x,
                                                   const float* __restrict__ xyz,
                                                   float* __restrict__ xs,
                                                   unsigned short* __restrict__ xst) {
    __shared__ float st[64][65];
    const int tid = threadIdx.x;
    const int n0 = blockIdx.x * 64, c0 = blockIdx.y * 64, b = blockIdx.z;
    const size_t base = ((size_t)b * C_ + c0) * N_ + n0;
#pragma unroll
    for (int r = 0; r < 4; ++r) {
        int c = r * 16 + (tid >> 4);
        int nc = (tid & 15) * 4;
        size_t off = base + (size_t)c * N_ + nc;
        float4 xv = *(const float4*)(x + off);
        float4 yv = *(const float4*)(xyz + off);
        float4 s = make_float4(xv.x + yv.x, xv.y + yv.y, xv.z + yv.z, xv.w + yv.w);
        *(float4*)(xs + off) = s;
        st[c][nc] = s.x; st[c][nc + 1] = s.y; st[c][nc + 2] = s.z; st[c][nc + 3] = s.w;
    }
    __syncthreads();
    int n = tid >> 2, cc = (tid & 3) * 16;
    short8v p0, p1;
#pragma unroll
    for (int j = 0; j < 8; ++j) {
        p0[j] = (short)f2bf(st[cc + j][n]);
        p1[j] = (short)f2bf(st[cc + 8 + j][n]);
    }
    size_t ob = ((size_t)b * N_ + n0 + n) * 256 + c0 + cc;
    *(short8v*)(xst + ob) = p0;
    *(short8v*)(xst + ob + 8) = p1;
}

// --------------------- Q-conv (MFMA): D[o][n], A=Wqk[o][c], B=xst[n][c]; out Qt[b][n][64] bf16
__global__ __launch_bounds__(256, 4) void convq_kernel(const unsigned short* __restrict__ xst,
                                                       const unsigned short* __restrict__ wh,
                                                       const float* __restrict__ bias,
                                                       unsigned short* __restrict__ Qt) {
    const int tid = threadIdx.x, wave = tid >> 6, lane = tid & 63, q = lane & 15, g = lane >> 4;
    const int n0 = blockIdx.x * 64, b = blockIdx.y;
    const unsigned short* xb = xst + (size_t)b * N_ * 256;
    f32x4 acc[4];
#pragma unroll
    for (int j = 0; j < 4; ++j) acc[j] = (f32x4){0.f, 0.f, 0.f, 0.f};
    for (int ks = 0; ks < 8; ++ks) {
        short8v aw = *(const short8v*)(wh + (size_t)(wave * 16 + q) * 256 + ks * 32 + 8 * g);
#pragma unroll
        for (int j = 0; j < 4; ++j) {
            short8v bx = *(const short8v*)(xb + (size_t)(n0 + j * 16 + q) * 256 + ks * 32 + 8 * g);
            acc[j] = __builtin_amdgcn_mfma_f32_16x16x32_bf16(aw, bx, acc[j], 0, 0, 0);
        }
    }
#pragma unroll
    for (int j = 0; j < 4; ++j) {
        short4v pk;
#pragma unroll
        for (int r = 0; r < 4; ++r)
            pk[r] = (short)f2bf(acc[j][r] + bias[wave * 16 + 4 * g + r]);
        *(short4v*)(Qt + ((size_t)b * N_ + n0 + j * 16 + q) * 64 + wave * 16 + 4 * g) = pk;
    }
}

// --------------------- V-conv (MFMA): D[n][o], A=xst[n][c], B=Wv^T; out Vh[b][c][n] bf16
__global__ __launch_bounds__(256, 4) void convv_kernel(const unsigned short* __restrict__ xst,
                                                       const unsigned short* __restrict__ wh,
                                                       const float* __restrict__ bias,
                                                       unsigned short* __restrict__ Vh) {
    const int tid = threadIdx.x, wave = tid >> 6, lane = tid & 63, q = lane & 15, g = lane >> 4;
    const int n0 = blockIdx.x * 64, o0 = blockIdx.y * 64, b = blockIdx.z;
    const unsigned short* xb = xst + (size_t)b * N_ * 256;
    f32x4 acc[4];
#pragma unroll
    for (int j = 0; j < 4; ++j) acc[j] = (f32x4){0.f, 0.f, 0.f, 0.f};
    for (int ks = 0; ks < 8; ++ks) {
        short8v bw = *(const short8v*)(wh + (size_t)(o0 + wave * 16 + q) * 256 + ks * 32 + 8 * g);
#pragma unroll
        for (int j = 0; j < 4; ++j) {
            short8v ax = *(const short8v*)(xb + (size_t)(n0 + j * 16 + q) * 256 + ks * 32 + 8 * g);
            acc[j] = __builtin_amdgcn_mfma_f32_16x16x32_bf16(ax, bw, acc[j], 0, 0, 0);
        }
    }
    float bo = bias[o0 + wave * 16 + q];
#pragma unroll
    for (int j = 0; j < 4; ++j) {
        short4v pk;
#pragma unroll
        for (int r = 0; r < 4; ++r) pk[r] = (short)f2bf(acc[j][r] + bo);
        *(short4v*)(Vh + ((size_t)b * C_ + o0 + wave * 16 + q) * N_ + n0 + j * 16 + 4 * g) = pk;
    }
}

// ------------------------------------------- pass A: per-row online softmax stats via MFMA
__global__ __launch_bounds__(256) void rowstats_mfma(const unsigned short* __restrict__ Qt,
                                                     float* __restrict__ pmax,
                                                     float* __restrict__ psum) {
    const int tid = threadIdx.x;
    const int wave = tid >> 6, lane = tid & 63, q = lane & 15, g = lane >> 4;
    const int bid = blockIdx.x;
    const int b  = bid & 7;
    const int it = (bid >> 3) & 63;
    const int js = bid >> 9;
    const int i0 = it * 64 + wave * 16;
    const unsigned short* Qb = Qt + (size_t)b * N_ * CQK_;

    const unsigned short* bp = Qb + (size_t)(i0 + q) * CQK_ + 8 * g;
    short8v bq0 = *(const short8v*)bp;
    short8v bq1 = *(const short8v*)(bp + 32);

    float m = -1e30f, s = 0.f;
    const int jbeg = js * (N_ / JS_);
    for (int j0 = jbeg; j0 < jbeg + N_ / JS_; j0 += 16) {
        const unsigned short* ap = Qb + (size_t)(j0 + q) * CQK_ + 8 * g;
        short8v a0 = *(const short8v*)ap;
        short8v a1 = *(const short8v*)(ap + 32);
        f32x4 e = {0.f, 0.f, 0.f, 0.f};
        e = __builtin_amdgcn_mfma_f32_16x16x32_bf16(a0, bq0, e, 0, 0, 0);
        e = __builtin_amdgcn_mfma_f32_16x16x32_bf16(a1, bq1, e, 0, 0, 0);
#pragma unroll
        for (int r = 0; r < 4; ++r) {
            float ee = e[r];
            float mn = fmaxf(m, ee);
            s = s * __expf(m - mn) + __expf(ee - mn);
            m = mn;
        }
    }
#pragma unroll
    for (int off = 16; off <= 32; off <<= 1) {
        float mo = __shfl_xor(m, off);
        float so = __shfl_xor(s, off);
        float mn = fmaxf(m, mo);
        s = s * __expf(m - mn) + so * __expf(mo - mn);
        m = mn;
    }
    if (lane < 16) {
        size_t o = ((size_t)js * B_ + b) * N_ + i0 + q;
        pmax[o] = m;
        psum[o] = s;
    }
}

__global__ __launch_bounds__(256) void rowmerge_kernel(const float* __restrict__ pmax,
                                                       const float* __restrict__ psum,
                                                       float* __restrict__ rm,
                                                       float* __restrict__ rsinv) {
    size_t i = (size_t)blockIdx.x * 256 + threadIdx.x;
    float m = -1e30f;
#pragma unroll
    for (int js = 0; js < JS_; ++js) m = fmaxf(m, pmax[(size_t)js * B_ * N_ + i]);
    float s = 0.f;
#pragma unroll
    for (int js = 0; js < JS_; ++js)
        s += psum[(size_t)js * B_ * N_ + i] * __expf(pmax[(size_t)js * B_ * N_ + i] - m);
    rm[i] = m;
    rsinv[i] = 1.f / s;
}

// --------- pass B (MFMA): energy -> attn (dbuf LDS, swizzled, b64 stores) -> PV -> fused diff
// outputs dh[b][m][c] bf16 = xs - xr/colsum  (transposed, ready as t-conv A-frags)
__global__ __launch_bounds__(512, 4) void pv_mfma(const unsigned short* __restrict__ Qt,
                                                  const unsigned short* __restrict__ Vh,
                                                  const float* __restrict__ rm,
                                                  const float* __restrict__ rsinv,
                                                  const float* __restrict__ xs,
                                                  unsigned short* __restrict__ dh) {
    __shared__ unsigned short saT[2][4096];   // [buf][m][n] bf16, 128B pitch, XOR-swizzled
    __shared__ float scs[8][2][16];
    __shared__ float scsf[64];
    const int tid = threadIdx.x;
    const int wave = tid >> 6, lane = tid & 63, q = lane & 15, g = lane >> 4;
    const int bid = blockIdx.x;
    const int b  = bid & 7;                // XCD-pinned: one batch per XCD
    const int m0 = (bid >> 3) << 6;
    const int nb = wave & 3, mp = wave >> 2;
    const unsigned short* Qb = Qt + (size_t)b * N_ * CQK_;
    const unsigned short* Vb = Vh + (size_t)b * C_ * N_;
    const float* rmb = rm + (size_t)b * N_;
    const float* rsb = rsinv + (size_t)b * N_;
    const float* xsb = xs + (size_t)b * C_ * N_;
    unsigned short* dhb = dh + (size_t)b * N_ * 256;

    short8v bqm[2][2];   // energy B-frags: Q columns m
#pragma unroll
    for (int mi = 0; mi < 2; ++mi) {
        const unsigned short* p = Qb + (size_t)(m0 + (mp * 2 + mi) * 16 + q) * CQK_ + 8 * g;
        bqm[mi][0] = *(const short8v*)p;
        bqm[mi][1] = *(const short8v*)(p + 32);
    }

    // preload tile-0 A-frags + stats
    const unsigned short* ap0 = Qb + (size_t)(nb * 16 + q) * CQK_ + 8 * g;
    short8v an0 = *(const short8v*)ap0;
    short8v an1 = *(const short8v*)(ap0 + 32);
    f32x4 rmc = *(const f32x4*)(rmb + nb * 16 + 4 * g);
    f32x4 rsc = *(const f32x4*)(rsb + nb * 16 + 4 * g);

    f32x4 acc[2][4];
#pragma unroll
    for (int ci = 0; ci < 2; ++ci)
#pragma unroll
        for (int mb = 0; mb < 4; ++mb) acc[ci][mb] = (f32x4){0.f, 0.f, 0.f, 0.f};
    float csum0 = 0.f, csum1 = 0.f;

    for (int n0 = 0; n0 < N_; n0 += 64) {
        const int cur = (n0 >> 6) & 1;
        // V-frags for current tile (consumed after barrier; latency under energy phase)
        short8v vf[2][2];
#pragma unroll
        for (int ch = 0; ch < 2; ++ch)
#pragma unroll
            for (int ci = 0; ci < 2; ++ci)
                vf[ch][ci] = *(const short8v*)(Vb + (size_t)(wave * 32 + ci * 16 + q) * N_
                                               + n0 + ch * 32 + 8 * g);
        // ---- energy + attn tile
#pragma unroll
        for (int mi = 0; mi < 2; ++mi) {
            f32x4 e = {0.f, 0.f, 0.f, 0.f};
            e = __builtin_amdgcn_mfma_f32_16x16x32_bf16(an0, bqm[mi][0], e, 0, 0, 0);
            e = __builtin_amdgcn_mfma_f32_16x16x32_bf16(an1, bqm[mi][1], e, 0, 0, 0);
            const int mcol = (mp * 2 + mi) * 16 + q;
            float csl = 0.f;
            short4v pk;
#pragma unroll
            for (int r = 0; r < 4; ++r) {
                float a = __expf(e[r] - rmc[r]) * rsc[r];
                csl += a;
                pk[r] = (short)f2bf(a);
            }
            if (mi == 0) csum0 += csl; else csum1 += csl;
            const int byte = mcol * 128 + ((2 * (nb * 16 + 4 * g)) ^ ((mcol & 7) << 4));
            *(short4v*)((char*)saT + cur * 8192 + byte) = pk;
        }
        // ---- prefetch next tile A-frags + stats
        const int n1 = (n0 + 64 < N_) ? n0 + 64 : 0;
        const unsigned short* apn = Qb + (size_t)(n1 + nb * 16 + q) * CQK_ + 8 * g;
        short8v an0n = *(const short8v*)apn;
        short8v an1n = *(const short8v*)(apn + 32);
        f32x4 rmn = *(const f32x4*)(rmb + n1 + nb * 16 + 4 * g);
        f32x4 rsn = *(const f32x4*)(rsb + n1 + nb * 16 + 4 * g);
        __syncthreads();   // attn tile visible; dbuf removes read-before-overwrite barrier
        // ---- PV
        __builtin_amdgcn_s_setprio(1);
#pragma unroll
        for (int ch = 0; ch < 2; ++ch) {
            short8v bfrag[4];
#pragma unroll
            for (int mb = 0; mb < 4; ++mb) {
                int row = mb * 16 + q;
                int byte = row * 128 + ((16 * (g + 4 * ch)) ^ ((row & 7) << 4));
                bfrag[mb] = *(const short8v*)((char*)saT + cur * 8192 + byte);
            }
#pragma unroll
            for (int ci = 0; ci < 2; ++ci)
#pragma unroll
                for (int mb = 0; mb < 4; ++mb)
                    acc[ci][mb] = __builtin_amdgcn_mfma_f32_16x16x32_bf16(vf[ch][ci], bfrag[mb],
                                                                          acc[ci][mb], 0, 0, 0);
        }
        __builtin_amdgcn_s_setprio(0);
        an0 = an0n; an1 = an1n; rmc = rmn; rsc = rsn;
    }

    // ---- column sums -> LDS broadcast
    csum0 += __shfl_xor(csum0, 16); csum0 += __shfl_xor(csum0, 32);
    csum1 += __shfl_xor(csum1, 16); csum1 += __shfl_xor(csum1, 32);
    if (lane < 16) { scs[wave][0][q] = csum0; scs[wave][1][q] = csum1; }
    __syncthreads();
    if (tid < 64) {
        int mb = tid >> 4, qq = tid & 15;
        int base = (mb >> 1) * 4;
        float cs = 0.f;
#pragma unroll
        for (int w = 0; w < 4; ++w) cs += scs[base + w][mb & 1][qq];
        scsf[tid] = cs;
    }
    __syncthreads();
    // ---- fused diff epilogue: dh[m][c] = bf16( xs[c][m] - acc/(1e-9+colsum[m]) )
#pragma unroll
    for (int ci = 0; ci < 2; ++ci) {
        int cb = wave * 32 + ci * 16 + 4 * g;
#pragma unroll
        for (int mb = 0; mb < 4; ++mb) {
            int m = m0 + mb * 16 + q;
            float inv = 1.f / (1e-9f + scsf[mb * 16 + q]);
            short4v pk;
#pragma unroll
            for (int r = 0; r < 4; ++r) {
                float xv = xsb[(size_t)(cb + r) * N_ + m];
                pk[r] = (short)f2bf(xv - acc[ci][mb][r] * inv);
            }
            *(short4v*)(dhb + (size_t)m * 256 + cb) = pk;
        }
    }
}

// ------- t-conv + finalize (MFMA): D[m][c], A=dh[m][c], B=Wt^T; out = xs + leaky(bn(t))
__global__ __launch_bounds__(256, 4) void convt_kernel(const unsigned short* __restrict__ dh,
                                                       const unsigned short* __restrict__ wh,
                                                       const float* __restrict__ bt,
                                                       const float* __restrict__ xs,
                                                       float* __restrict__ out,
                                                       const float* __restrict__ gam,
                                                       const float* __restrict__ bet,
                                                       const float* __restrict__ mu,
                                                       const float* __restrict__ var) {
    const int tid = threadIdx.x, wave = tid >> 6, lane = tid & 63, q = lane & 15, g = lane >> 4;
    const int m0 = blockIdx.x * 64, c0 = blockIdx.y * 64, b = blockIdx.z;
    const unsigned short* db = dh + (size_t)b * N_ * 256;
    f32x4 acc[4];
#pragma unroll
    for (int j = 0; j < 4; ++j) acc[j] = (f32x4){0.f, 0.f, 0.f, 0.f};
    for (int ks = 0; ks < 8; ++ks) {
        short8v bw = *(const short8v*)(wh + (size_t)(c0 + wave * 16 + q) * 256 + ks * 32 + 8 * g);
#pragma unroll
        for (int j = 0; j < 4; ++j) {
            short8v ad = *(const short8v*)(db + (size_t)(m0 + j * 16 + q) * 256 + ks * 32 + 8 * g);
            acc[j] = __builtin_amdgcn_mfma_f32_16x16x32_bf16(ad, bw, acc[j], 0, 0, 0);
        }
    }
    const int c = c0 + wave * 16 + q;
    const float sc = rsqrtf(var[c] + 1e-5f) * gam[c];
    const float sh = bet[c] - mu[c] * sc;
    const float bb = bt[c];
#pragma unroll
    for (int j = 0; j < 4; ++j) {
        size_t off = ((size_t)b * C_ + c) * N_ + m0 + j * 16 + 4 * g;
        float4 xv = *(const float4*)(xs + off);
        float4 o;
        float tn;
        tn = (acc[j][0] + bb) * sc + sh; o.x = xv.x + (tn >= 0.f ? tn : 0.2f * tn);
        tn = (acc[j][1] + bb) * sc + sh; o.y = xv.y + (tn >= 0.f ? tn : 0.2f * tn);
        tn = (acc[j][2] + bb) * sc + sh; o.z = xv.z + (tn >= 0.f ? tn : 0.2f * tn);
        tn = (acc[j][3] + bb) * sc + sh; o.w = xv.w + (tn >= 0.f ? tn : 0.2f * tn);
        *(float4*)(out + off) = o;
    }
}

// ----------------------------------------------------------------------------------------
extern "C" void kernel_launch(void* const* d_in, const int* in_sizes, int n_in,
                              void* d_out, int out_size, void* d_ws, size_t ws_size,
                              hipStream_t stream) {
    (void)in_sizes; (void)n_in; (void)out_size; (void)ws_size;
    const float* x   = (const float*)d_in[0];
    const float* xyz = (const float*)d_in[1];
    const float* wqk = (const float*)d_in[2];
    const float* bqk = (const float*)d_in[3];
    const float* wv  = (const float*)d_in[4];
    const float* bv  = (const float*)d_in[5];
    const float* wt  = (const float*)d_in[6];
    const float* bt  = (const float*)d_in[7];
    const float* gam = (const float*)d_in[8];
    const float* bet = (const float*)d_in[9];
    const float* mu  = (const float*)d_in[10];
    const float* var = (const float*)d_in[11];
    float* out = (float*)d_out;

    const size_t M8 = (size_t)B_ * C_ * N_;   // 8M floats
    float* ws = (float*)d_ws;
    size_t off = 0;
    float* xs = ws + off;                         off += M8;        // fp32 [b][c][n]
    unsigned short* xst = (unsigned short*)(ws + off); off += M8 / 2;  // bf16 [b][n][c]
    unsigned short* Qt  = (unsigned short*)(ws + off); off += M8 / 8;  // bf16 [b][n][64]
    unsigned short* Vh  = (unsigned short*)(ws + off); off += M8 / 2;  // bf16 [b][c][n]
    unsigned short* wh  = (unsigned short*)(ws + off); off += 81920;   // bf16 weights
    float* pmax = ws + off; off += (size_t)JS_ * B_ * N_;
    float* psum = ws + off; off += (size_t)JS_ * B_ * N_;
    float* rmb  = ws + off; off += (size_t)B_ * N_;
    float* rsb  = ws + off; off += (size_t)B_ * N_;
    unsigned short* dhb = xst;   // alias: xst dead after conv_q/conv_v; pv writes dh here

    wcvt_kernel<<<dim3(144), dim3(256), 0, stream>>>(wqk, wv, wt, wh);
    addt_kernel<<<dim3(N_ / 64, C_ / 64, B_), dim3(256), 0, stream>>>(x, xyz, xs, xst);
    convq_kernel<<<dim3(N_ / 64, B_), dim3(256), 0, stream>>>(xst, wh, bqk, Qt);
    convv_kernel<<<dim3(N_ / 64, C_ / 64, B_), dim3(256), 0, stream>>>(xst, wh + 16384, bv, Vh);
    rowstats_mfma<<<dim3(B_ * (N_ / 64) * JS_), dim3(256), 0, stream>>>(Qt, pmax, psum);
    rowmerge_kernel<<<dim3(B_ * N_ / 256), dim3(256), 0, stream>>>(pmax, psum, rmb, rsb);
    pv_mfma<<<dim3(B_ * N_ / 64), dim3(512), 0, stream>>>(Qt, Vh, rmb, rsb, xs, dhb);
    convt_kernel<<<dim3(N_ / 64, C_ / 64, B_), dim3(256), 0, stream>>>(
        dhb, wh + 81920, bt, xs, out, gam, bet, mu, var);
}